// Round 6
// baseline (202.679 us; speedup 1.0000x reference)
//
#include <hip/hip_runtime.h>

// StyleGAN2 modulated transposed conv block, MI355X bf16-MFMA implementation.
// R6: conv restructured: A (activations) global->register direct, ping-pong in
//     regs (unroll-2); only B (weights) via 16KB double-buffered LDS with
//     counted vmcnt(6); 128x128 tile acc[4][4] (~200 regs -> 3 blocks/CU).

typedef unsigned short u16;
typedef unsigned int u32;
typedef __bf16 bf16x8 __attribute__((ext_vector_type(8)));
typedef u16 u16x8 __attribute__((ext_vector_type(8)));
typedef float f32x4 __attribute__((ext_vector_type(4)));

#define CIN 512
#define COUT 256
#define XP 33   // padded xs spatial (32 + 1)
#define YP 68   // padded y spatial (64 + 2*2)
#define RS (XP*512)   // xs row stride in u16 = 16896

#define XS_BYTES  (16u*33*33*512*2)        // 17,842,176
#define YP_BYTES  (16u*68*68*256*2)        // 37,879,808
#define WBT_BYTES (9u*256*512*2)           //  2,359,296
#define WSQ_BYTES (512u*256*4)             //    524,288
#define STY_BYTES (16u*512*4)              //     32,768
#define DEM_BYTES (16u*256*4)              //     16,384

__device__ __forceinline__ u16 f2bf(float f) {
    u32 u = __float_as_uint(f);
    u32 r = (u + 0x7fffu + ((u >> 16) & 1u)) >> 16;
    return (u16)r;
}

__device__ __forceinline__ void gload16(const void* g, void* l) {
    __builtin_amdgcn_global_load_lds(
        (const __attribute__((address_space(1))) u32*)g,
        (__attribute__((address_space(3))) u32*)l, 16, 0, 0);
}

// ---------------- style: style[b,ci] = s[b,:]·mod_w[ci,:]/sqrt(512) + mod_b[ci] -----
__global__ __launch_bounds__(256)
void style_kernel(const float* __restrict__ s, const float* __restrict__ mod_w,
                  const float* __restrict__ mod_b, float* __restrict__ style) {
    int b = blockIdx.x, t = threadIdx.x;
    __shared__ float ss[512];
    for (int i = t; i < 512; i += 256) ss[i] = s[b*512 + i];
    __syncthreads();
    for (int ci = t; ci < 512; ci += 256) {
        const float* row = mod_w + (size_t)ci * 512;
        float acc = 0.f;
        for (int k = 0; k < 512; k += 4) {
            float4 m = *reinterpret_cast<const float4*>(row + k);
            acc += m.x*ss[k] + m.y*ss[k+1] + m.z*ss[k+2] + m.w*ss[k+3];
        }
        style[b*512 + ci] = acc * 0.04419417382415922f + mod_b[ci];
    }
}

// ---------------- wsq[ci,co] = sum_k weight[ci,co,:,:]^2 ----------------------------
__global__ __launch_bounds__(256)
void wsq_kernel(const float* __restrict__ weight, float* __restrict__ wsq) {
    int idx = blockIdx.x * 256 + threadIdx.x;   // 512*256
    const float* p = weight + (size_t)idx * 9;
    float a = 0.f;
    #pragma unroll
    for (int i = 0; i < 9; ++i) { float v = p[i]; a += v * v; }
    wsq[idx] = a;
}

// ---------------- demod[b,co] = rsqrt(sum_ci style^2*wsq/4608 + 1e-8) ---------------
__global__ __launch_bounds__(256)
void demod_kernel(const float* __restrict__ style, const float* __restrict__ wsq,
                  float* __restrict__ demod) {
    int b = blockIdx.x, t = threadIdx.x;   // t == co
    __shared__ float st2[512];
    for (int i = t; i < 512; i += 256) { float v = style[b*512 + i]; st2[i] = v * v; }
    __syncthreads();
    float acc = 0.f;
    for (int ci = 0; ci < 512; ++ci) acc += st2[ci] * wsq[ci*256 + t];
    demod[b*256 + t] = rsqrtf(acc * (1.0f/4608.0f) + 1e-8f);
}

// ---------------- wbT[p][co][ci] = bf16(weight[ci][co][kh][kw]), p = kh*3+kw --------
__global__ __launch_bounds__(256)
void wbt_kernel(const float* __restrict__ weight, u16* __restrict__ wbT) {
    int bid = blockIdx.x;            // 0..2303
    int p = bid >> 8, co = bid & 255;
    int t = threadIdx.x;
    u16* dst = wbT + ((size_t)p*256 + co)*512;
    const float* srcb = weight + co*9 + p;
    dst[t]       = f2bf(srcb[(size_t)t * 2304]);
    dst[t + 256] = f2bf(srcb[(size_t)(t + 256) * 2304]);
}

// ---------------- norm: xs[b][h][w][ci] = x*rsqrt(mean_ci x^2 + eps)*style/sqrt4608 -
// grid (33,16): h==32 blocks zero the pad row; others compute + zero w=32 column.
__global__ __launch_bounds__(256)
void norm_kernel(const float* __restrict__ x, const float* __restrict__ style,
                 u16* __restrict__ xs) {
    int h = blockIdx.x, b = blockIdx.y;
    int t = threadIdx.x;
    u16* xrow = xs + ((size_t)b*XP + h)*XP*512;
    if (h == 32) {                       // zero entire pad row (33*512 u16)
        u16x8 z = {0,0,0,0,0,0,0,0};
        for (int i = t; i < 2112; i += 256)
            reinterpret_cast<u16x8*>(xrow)[i] = z;
        return;
    }
    __shared__ float red[8][32];
    __shared__ float sscale[32];
    __shared__ float sstyle[512];
    __shared__ u16 tile[32*512];
    for (int i = t; i < 512; i += 256)
        sstyle[i] = style[b*512 + i] * 0.014731391274719739f;  // 1/sqrt(4608)
    int w = t & 31, cg = t >> 5;
    const float* xb = x + ((size_t)b*512*32 + h)*32;   // + ci*1024 + w

    float vv[64];
    float a = 0.f;
    #pragma unroll
    for (int i = 0; i < 64; ++i) {
        float v = xb[(size_t)(8*i + cg)*1024 + w];
        vv[i] = v;
        a += v * v;
    }
    red[cg][w] = a;
    __syncthreads();
    if (t < 32) {
        float s2 = 0.f;
        #pragma unroll
        for (int g = 0; g < 8; ++g) s2 += red[g][t];
        sscale[t] = rsqrtf(s2 * (1.0f/512.0f) + 1e-8f);
    }
    __syncthreads();
    float sc = sscale[w];
    #pragma unroll
    for (int i = 0; i < 64; ++i) {
        int ci = 8*i + cg;
        float v = vv[i] * sc * sstyle[ci];
        tile[w*512 + ((i ^ (w & 7)) * 8 + cg)] = f2bf(v);
    }
    // zero the w=32 pad column for this row (512 u16 = 64 u16x8)
    if (t < 64) {
        u16x8 z = {0,0,0,0,0,0,0,0};
        reinterpret_cast<u16x8*>(xrow + 32*512)[t] = z;
    }
    __syncthreads();
    int wv = t >> 6, gi = t & 63;
    #pragma unroll
    for (int rr = 0; rr < 32; rr += 4) {
        int w2 = rr + wv;
        u16x8 v = *reinterpret_cast<const u16x8*>(&tile[w2*512 + ((gi ^ (w2 & 7)) * 8)]);
        *reinterpret_cast<u16x8*>(&xrow[w2*512 + gi*8]) = v;
    }
}

// ---------------- conv: parity-class implicit GEMM, A-in-reg, B-in-LDS --------------
// class (py,px): y[2a+py, 2b+px] = sum_taps sum_ci xs[a+dy, b+dx, ci] * W[kh,kw][ci,co]
// tile 128Mx128N, 4 waves (2Mx2N, each 64x64): per K=32 step/wave:
//   4 A-frags direct global->reg (ping-pong), 4 B ds_read_b128, 16 MFMA.
__global__ __launch_bounds__(256)
void conv_mfma_kernel(const u16* __restrict__ xs, const u16* __restrict__ wbT,
                      const float* __restrict__ demod, const float* __restrict__ bias,
                      u16* __restrict__ ypad) {
    __shared__ __align__(16) u16 Blds[2][4096];   // per buf: B[128 rows][32k] = 8KB

    const int xx = blockIdx.x;         // 0..15
    const int nt = xx & 1, mt = xx >> 1;
    const int zz = blockIdx.y;         // 0..63
    // balanced mapping: ids 0..255 alt {cls3,cls2}; 256..511 alt {cls0,cls1}
    int cls, b;
    if (zz < 32) { cls = (zz & 1) ? 2 : 3; b = zz >> 1; }
    else         { cls = (zz & 1) ? 1 : 0; b = (zz - 32) >> 1; }
    const int py = cls >> 1, px = cls & 1;

    int ntaps;
    int aof0=0, aof1=0, aof2=0, aof3=0;
    int bof0=0, bof1=0, bof2=0, bof3=0;
    if (cls == 0)      { ntaps=1; aof0=0;        bof0=4*131072; }
    else if (cls == 1) { ntaps=2; aof0=512;      bof0=3*131072;
                                  aof1=0;        bof1=5*131072; }
    else if (cls == 2) { ntaps=2; aof0=RS;       bof0=1*131072;
                                  aof1=0;        bof1=7*131072; }
    else               { ntaps=4; aof0=RS+512;   bof0=0;
                                  aof1=RS;       bof1=2*131072;
                                  aof2=512;      bof2=6*131072;
                                  aof3=0;        bof3=8*131072; }

    const int t = threadIdx.x;
    const int lane = t & 63, wid = t >> 6;
    const int wm0 = (wid >> 1) * 64;       // M half: 0 / 64
    const int wn0 = (wid & 1) * 64;        // N half: 0 / 64 (within 128-tile)
    const int rl = lane & 15, ql = lane >> 4;
    const int qs = (ql ^ ((rl >> 1) & 3)) * 8;   // swizzled LDS read granule (u16)
    const int a0 = mt * 4;
    const int n0 = nt * 128;

    // B staging: thread t stages rows (t>>2) and (t>>2)+64, swizzled source granule
    const int c8 = (((t & 3) ^ ((t >> 3) & 3))) * 8;
    const u16* bB = wbT + (n0 + (t >> 2))*512 + c8;

    // A fragment base pointers (per mi), per-lane
    const u16* aBase[4];
    #pragma unroll
    for (int mi = 0; mi < 4; ++mi)
        aBase[mi] = xs + (size_t)b*XP*RS
                  + ((a0 + (wm0 >> 5) + (mi >> 1))*XP + (mi & 1)*16 + rl)*512 + ql*8;

    f32x4 acc[4][4];
    #pragma unroll
    for (int i = 0; i < 4; ++i)
        #pragma unroll
        for (int j = 0; j < 4; ++j) { f32x4 z = {0.f,0.f,0.f,0.f}; acc[i][j] = z; }

    const int S = ntaps << 4;   // always even (16/32/64)

    auto aoff = [&](int tap) { return (tap == 0) ? aof0 : (tap == 1) ? aof1
                                     : (tap == 2) ? aof2 : aof3; };
    auto boff = [&](int tap) { return (tap == 0) ? bof0 : (tap == 1) ? bof1
                                     : (tap == 2) ? bof2 : bof3; };

    bf16x8 aP[4], aQ[4];

    // prologue: A(0) -> aP, B(0) -> buf0
    {
        int ao = aoff(0);
        #pragma unroll
        for (int mi = 0; mi < 4; ++mi)
            aP[mi] = *reinterpret_cast<const bf16x8*>(aBase[mi] + ao);
        int bo = boff(0);
        gload16(bB + bo,         &Blds[0][t*8]);
        gload16(bB + bo + 32768, &Blds[0][t*8 + 2048]);
    }

    #define CONV_STEP(s_, aCur, aNxt, buf_)                                          \
    {                                                                                \
        int s1 = (s_) + 1;                                                           \
        if (s1 < S) {                                                                \
            int tap1 = s1 >> 4;                                                      \
            int k01 = (s1 & 15) << 5;                                                \
            int ao1 = aoff(tap1) + k01;                                              \
            _Pragma("unroll")                                                        \
            for (int mi = 0; mi < 4; ++mi)                                           \
                aNxt[mi] = *reinterpret_cast<const bf16x8*>(aBase[mi] + ao1);        \
            int bo1 = boff(tap1) + k01;                                              \
            gload16(bB + bo1,         &Blds[(buf_) ^ 1][t*8]);                       \
            gload16(bB + bo1 + 32768, &Blds[(buf_) ^ 1][t*8 + 2048]);                \
            asm volatile("s_waitcnt vmcnt(6)" ::: "memory");                         \
        } else {                                                                     \
            asm volatile("s_waitcnt vmcnt(0)" ::: "memory");                         \
        }                                                                            \
        __builtin_amdgcn_s_barrier();      /* B(s) staged by all waves */            \
        bf16x8 bfr[4];                                                               \
        _Pragma("unroll")                                                            \
        for (int ni = 0; ni < 4; ++ni)                                               \
            bfr[ni] = *reinterpret_cast<const bf16x8*>(                              \
                &Blds[buf_][(wn0 + ni*16 + rl)*32 + qs]);                            \
        asm volatile("s_waitcnt lgkmcnt(0)" ::: "memory");                           \
        __builtin_amdgcn_sched_barrier(0);                                           \
        __builtin_amdgcn_s_barrier();      /* all waves done reading buf */          \
        __builtin_amdgcn_s_setprio(1);                                               \
        _Pragma("unroll")                                                            \
        for (int mi = 0; mi < 4; ++mi)                                               \
            _Pragma("unroll")                                                        \
            for (int ni = 0; ni < 4; ++ni)                                           \
                acc[mi][ni] = __builtin_amdgcn_mfma_f32_16x16x32_bf16(               \
                    aCur[mi], bfr[ni], acc[mi][ni], 0, 0, 0);                        \
        __builtin_amdgcn_s_setprio(0);                                               \
    }

    for (int s = 0; s < S; s += 2) {
        CONV_STEP(s,     aP, aQ, 0);
        CONV_STEP(s + 1, aQ, aP, 1);
    }
    #undef CONV_STEP

    // epilogue: val = acc*demod[b,co] + bias[co], write bf16 into padded channel-last y
    float dmv[4], bsv[4];
    #pragma unroll
    for (int ni = 0; ni < 4; ++ni) {
        int co = n0 + wn0 + ni*16 + rl;
        dmv[ni] = demod[b*256 + co];
        bsv[ni] = bias[co];
    }
    #pragma unroll
    for (int mi = 0; mi < 4; ++mi) {
        #pragma unroll
        for (int rg = 0; rg < 4; ++rg) {
            int m = wm0 + mi*16 + ql*4 + rg;
            int ar = a0 + (m >> 5), bc = m & 31;
            int oy = 2*ar + py + 2, ox = 2*bc + px + 2;
            size_t rowbase = (((size_t)b*YP + oy)*YP + ox)*256;
            #pragma unroll
            for (int ni = 0; ni < 4; ++ni) {
                int co = n0 + wn0 + ni*16 + rl;
                float v = acc[mi][ni][rg] * dmv[ni] + bsv[ni];
                ypad[rowbase + co] = f2bf(v);
            }
        }
    }
}

// ---------------- blur: separable 5x5 binomial + lrelu*sqrt2, bf16 NHWC -> f32 NCHW -
__global__ __launch_bounds__(256)
void blur_kernel(const u16* __restrict__ ypad, float* __restrict__ out) {
    const int cg = blockIdx.x;   // 0..3 (64-channel chunk)
    const int oy = blockIdx.y;   // 0..63
    const int b  = blockIdx.z;
    const int t = threadIdx.x;
    __shared__ float vlds[68][65];   // [cx][ch]

    const int cp  = t & 31;      // channel pair
    const int cxi = t >> 5;      // 0..7
    const float wv0 = (oy >= 2) ? 0.0625f : 0.f;
    const float wv1 = (oy >= 1) ? 0.25f   : 0.f;
    const float wv2 = 0.375f;
    const float wv3 = (oy <= 62) ? 0.25f   : 0.f;
    const float wv4 = (oy <= 61) ? 0.0625f : 0.f;
    const u16* base = ypad + ((size_t)b*YP + oy)*YP*256 + cg*64 + cp*2;

    #pragma unroll
    for (int j = 0; j < 9; ++j) {
        int cx = j*8 + cxi;
        if (cx < 68) {
            float a0 = 0.f, a1 = 0.f;
            if (cx >= 2 && cx <= 65) {
                const u16* p = base + cx*256;
                u32 u0 = *reinterpret_cast<const u32*>(p);
                u32 u1 = *reinterpret_cast<const u32*>(p + YP*256);
                u32 u2 = *reinterpret_cast<const u32*>(p + 2*YP*256);
                u32 u3 = *reinterpret_cast<const u32*>(p + 3*YP*256);
                u32 u4 = *reinterpret_cast<const u32*>(p + 4*YP*256);
                a0 = wv0*__uint_as_float(u0 << 16) + wv1*__uint_as_float(u1 << 16)
                   + wv2*__uint_as_float(u2 << 16) + wv3*__uint_as_float(u3 << 16)
                   + wv4*__uint_as_float(u4 << 16);
                a1 = wv0*__uint_as_float(u0 & 0xffff0000u) + wv1*__uint_as_float(u1 & 0xffff0000u)
                   + wv2*__uint_as_float(u2 & 0xffff0000u) + wv3*__uint_as_float(u3 & 0xffff0000u)
                   + wv4*__uint_as_float(u4 & 0xffff0000u);
            }
            vlds[cx][cp*2]     = a0;
            vlds[cx][cp*2 + 1] = a1;
        }
    }
    __syncthreads();

    const int oxl = t & 63;
    const int cq  = t >> 6;      // 0..3
    float* ob = out + (((size_t)b*256 + cg*64)*64 + oy)*64;
    #pragma unroll
    for (int i = 0; i < 16; ++i) {
        int c = cq*16 + i;
        float v = 0.0625f*vlds[oxl][c] + 0.25f*vlds[oxl+1][c] + 0.375f*vlds[oxl+2][c]
                + 0.25f*vlds[oxl+3][c] + 0.0625f*vlds[oxl+4][c];
        v = (v >= 0.f ? v : 0.2f*v) * 1.4142135623730951f;
        ob[(size_t)c*4096 + oxl] = v;
    }
}

extern "C" void kernel_launch(void* const* d_in, const int* in_sizes, int n_in,
                              void* d_out, int out_size, void* d_ws, size_t ws_size,
                              hipStream_t stream) {
    const float* x      = (const float*)d_in[0];
    const float* s      = (const float*)d_in[1];
    const float* weight = (const float*)d_in[2];
    const float* bias   = (const float*)d_in[3];
    const float* mod_w  = (const float*)d_in[4];
    const float* mod_b  = (const float*)d_in[5];
    float* out = (float*)d_out;

    char* ws = (char*)d_ws;
    size_t off = 0;
    u16*   xs    = (u16*)(ws + off); off += XS_BYTES;
    u16*   ypad  = (u16*)(ws + off); off += YP_BYTES;
    u16*   wbT   = (u16*)(ws + off); off += WBT_BYTES;
    float* wsq   = (float*)(ws + off); off += WSQ_BYTES;
    float* style = (float*)(ws + off); off += STY_BYTES;
    float* demod = (float*)(ws + off); off += DEM_BYTES;
    if (ws_size < off) return;  // workspace too small -> visible correctness failure

    style_kernel<<<16, 256, 0, stream>>>(s, mod_w, mod_b, style);
    wsq_kernel<<<512, 256, 0, stream>>>(weight, wsq);
    demod_kernel<<<16, 256, 0, stream>>>(style, wsq, demod);
    wbt_kernel<<<2304, 256, 0, stream>>>(weight, wbT);
    norm_kernel<<<dim3(33, 16), 256, 0, stream>>>(x, style, xs);
    conv_mfma_kernel<<<dim3(16, 64), 256, 0, stream>>>(xs, wbT, demod, bias, ypad);
    blur_kernel<<<dim3(4, 64, 16), 256, 0, stream>>>(ypad, out);
}

// Round 7
// 134.316 us; speedup vs baseline: 1.5090x; 1.5090x over previous
//
#include <hip/hip_runtime.h>

// StyleGAN2 modulated transposed conv block, MI355X bf16-MFMA implementation.
// R7: conv reverted to R5 (proven 81us: 128Mx256N, 2-buf issue-then-wait vmcnt(6),
//     balanced class pairing); blur = 4-rows-per-block register-reuse separable;
//     {style,wsq} and {demod,wbt} fused into two wide dispatches.

typedef unsigned short u16;
typedef unsigned int u32;
typedef __bf16 bf16x8 __attribute__((ext_vector_type(8)));
typedef u16 u16x8 __attribute__((ext_vector_type(8)));
typedef float f32x4 __attribute__((ext_vector_type(4)));

#define CIN 512
#define COUT 256
#define XP 33   // padded xs spatial (32 + 1)
#define YP 68   // padded y spatial (64 + 2*2)
#define RS (XP*512)   // xs row stride in u16 = 16896

#define XS_BYTES  (16u*33*33*512*2)        // 17,842,176
#define YP_BYTES  (16u*68*68*256*2)        // 37,879,808
#define WBT_BYTES (9u*256*512*2)           //  2,359,296
#define WSQ_BYTES (512u*256*4)             //    524,288
#define STY_BYTES (16u*512*4)              //     32,768
#define DEM_BYTES (16u*256*4)              //     16,384

__device__ __forceinline__ u16 f2bf(float f) {
    u32 u = __float_as_uint(f);
    u32 r = (u + 0x7fffu + ((u >> 16) & 1u)) >> 16;
    return (u16)r;
}

__device__ __forceinline__ void gload16(const void* g, void* l) {
    __builtin_amdgcn_global_load_lds(
        (const __attribute__((address_space(1))) u32*)g,
        (__attribute__((address_space(3))) u32*)l, 16, 0, 0);
}

// ---------------- fuseA: style (64 blocks) + wsq (512 blocks) -----------------------
// style[b,ci] = s[b,:]·mod_w[ci,:]/sqrt(512) + mod_b[ci]
// wsq[ci,co]  = sum_k weight[ci,co,:,:]^2
__global__ __launch_bounds__(256)
void fuseA_kernel(const float* __restrict__ s, const float* __restrict__ mod_w,
                  const float* __restrict__ mod_b, const float* __restrict__ weight,
                  float* __restrict__ style, float* __restrict__ wsq) {
    int bid = blockIdx.x, t = threadIdx.x;
    if (bid < 64) {
        int b = bid >> 2, q = bid & 3;
        __shared__ float ss[512];
        for (int i = t; i < 512; i += 256) ss[i] = s[b*512 + i];
        __syncthreads();
        int ci = q*128 + (t >> 1);
        int kh = (t & 1) * 256;
        const float* row = mod_w + (size_t)ci * 512 + kh;
        const float* sh = ss + kh;
        float acc = 0.f;
        for (int k = 0; k < 256; k += 4) {
            float4 m = *reinterpret_cast<const float4*>(row + k);
            acc += m.x*sh[k] + m.y*sh[k+1] + m.z*sh[k+2] + m.w*sh[k+3];
        }
        acc += __shfl_xor(acc, 1);
        if (!(t & 1)) style[b*512 + ci] = acc * 0.04419417382415922f + mod_b[ci];
    } else {
        int idx = (bid - 64) * 256 + t;   // 512*256
        const float* p = weight + (size_t)idx * 9;
        float a = 0.f;
        #pragma unroll
        for (int i = 0; i < 9; ++i) { float v = p[i]; a += v * v; }
        wsq[idx] = a;
    }
}

// ---------------- fuseB: demod (64 blocks) + wbt (2304 blocks) ----------------------
// demod[b,co] = rsqrt(sum_ci style^2*wsq/4608 + 1e-8)
// wbT[p][co][ci] = bf16(weight[ci][co][kh][kw]), p = kh*3+kw
__global__ __launch_bounds__(256)
void fuseB_kernel(const float* __restrict__ style, const float* __restrict__ wsq,
                  const float* __restrict__ weight, float* __restrict__ demod,
                  u16* __restrict__ wbT) {
    int bid = blockIdx.x, t = threadIdx.x;
    if (bid < 64) {
        int b = bid >> 2, q = bid & 3;
        __shared__ float st2[512];
        for (int i = t; i < 512; i += 256) { float v = style[b*512 + i]; st2[i] = v * v; }
        __syncthreads();
        int co = q*64 + (t >> 2);
        int kq = (t & 3) * 128;
        float acc = 0.f;
        for (int ci = kq; ci < kq + 128; ++ci) acc += st2[ci] * wsq[ci*256 + co];
        acc += __shfl_xor(acc, 1);
        acc += __shfl_xor(acc, 2);
        if (!(t & 3)) demod[b*256 + co] = rsqrtf(acc * (1.0f/4608.0f) + 1e-8f);
    } else {
        int id = bid - 64;               // 0..2303
        int p = id >> 8, co = id & 255;
        u16* dst = wbT + ((size_t)p*256 + co)*512;
        const float* srcb = weight + co*9 + p;
        dst[t]       = f2bf(srcb[(size_t)t * 2304]);
        dst[t + 256] = f2bf(srcb[(size_t)(t + 256) * 2304]);
    }
}

// ---------------- norm: xs[b][h][w][ci] = x*rsqrt(mean_ci x^2 + eps)*style/sqrt4608 -
// grid (33,16): h==32 blocks zero the pad row; others compute + zero w=32 column.
__global__ __launch_bounds__(256)
void norm_kernel(const float* __restrict__ x, const float* __restrict__ style,
                 u16* __restrict__ xs) {
    int h = blockIdx.x, b = blockIdx.y;
    int t = threadIdx.x;
    u16* xrow = xs + ((size_t)b*XP + h)*XP*512;
    if (h == 32) {                       // zero entire pad row (33*512 u16)
        u16x8 z = {0,0,0,0,0,0,0,0};
        for (int i = t; i < 2112; i += 256)
            reinterpret_cast<u16x8*>(xrow)[i] = z;
        return;
    }
    __shared__ float red[8][32];
    __shared__ float sscale[32];
    __shared__ float sstyle[512];
    __shared__ u16 tile[32*512];
    for (int i = t; i < 512; i += 256)
        sstyle[i] = style[b*512 + i] * 0.014731391274719739f;  // 1/sqrt(4608)
    int w = t & 31, cg = t >> 5;
    const float* xb = x + ((size_t)b*512*32 + h)*32;   // + ci*1024 + w

    float vv[64];
    float a = 0.f;
    #pragma unroll
    for (int i = 0; i < 64; ++i) {
        float v = xb[(size_t)(8*i + cg)*1024 + w];
        vv[i] = v;
        a += v * v;
    }
    red[cg][w] = a;
    __syncthreads();
    if (t < 32) {
        float s2 = 0.f;
        #pragma unroll
        for (int g = 0; g < 8; ++g) s2 += red[g][t];
        sscale[t] = rsqrtf(s2 * (1.0f/512.0f) + 1e-8f);
    }
    __syncthreads();
    float sc = sscale[w];
    #pragma unroll
    for (int i = 0; i < 64; ++i) {
        int ci = 8*i + cg;
        float v = vv[i] * sc * sstyle[ci];
        tile[w*512 + ((i ^ (w & 7)) * 8 + cg)] = f2bf(v);
    }
    // zero the w=32 pad column for this row (512 u16 = 64 u16x8)
    if (t < 64) {
        u16x8 z = {0,0,0,0,0,0,0,0};
        reinterpret_cast<u16x8*>(xrow + 32*512)[t] = z;
    }
    __syncthreads();
    int wv = t >> 6, gi = t & 63;
    #pragma unroll
    for (int rr = 0; rr < 32; rr += 4) {
        int w2 = rr + wv;
        u16x8 v = *reinterpret_cast<const u16x8*>(&tile[w2*512 + ((gi ^ (w2 & 7)) * 8)]);
        *reinterpret_cast<u16x8*>(&xrow[w2*512 + gi*8]) = v;
    }
}

// ---------------- conv: parity-class implicit GEMM, 128x256 tile, 2-buf pipeline ----
// class (py,px): y[2a+py, 2b+px] = sum_taps sum_ci xs[a+dy, b+dx, ci] * W[kh,kw][ci,co]
// 4 waves (2Mx2N), each 64Mx128N: 12 ds_read_b128 / 32 MFMA per K-step.
__global__ __launch_bounds__(256)
void conv_mfma_kernel(const u16* __restrict__ xs, const u16* __restrict__ wbT,
                      const float* __restrict__ demod, const float* __restrict__ bias,
                      u16* __restrict__ ypad) {
    // per buf (12288 u16 = 24KB): A[128][32] @0, B[256][32] @4096
    __shared__ __align__(16) u16 sm[2*12288];

    const int mt = blockIdx.x;         // 0..7  M-tile
    const int zz = blockIdx.y;         // 0..63
    // balanced mapping: ids 0..255 alt {cls3,cls2}; 256..511 alt {cls0,cls1}
    int cls, b;
    if (zz < 32) { cls = (zz & 1) ? 2 : 3; b = zz >> 1; }
    else         { cls = (zz & 1) ? 1 : 0; b = (zz - 32) >> 1; }
    const int py = cls >> 1, px = cls & 1;

    int ntaps;
    int aof0=0, aof1=0, aof2=0, aof3=0;
    int bof0=0, bof1=0, bof2=0, bof3=0;
    if (cls == 0)      { ntaps=1; aof0=0;        bof0=4*131072; }
    else if (cls == 1) { ntaps=2; aof0=512;      bof0=3*131072;
                                  aof1=0;        bof1=5*131072; }
    else if (cls == 2) { ntaps=2; aof0=RS;       bof0=1*131072;
                                  aof1=0;        bof1=7*131072; }
    else               { ntaps=4; aof0=RS+512;   bof0=0;
                                  aof1=RS;       bof1=2*131072;
                                  aof2=512;      bof2=6*131072;
                                  aof3=0;        bof3=8*131072; }

    const int t = threadIdx.x;
    const int lane = t & 63, wid = t >> 6;
    const int wm0 = (wid >> 1) * 64;       // M half: 0 / 64
    const int wn0 = (wid & 1) * 128;       // N half: 0 / 128
    const int r = lane & 15, q = lane >> 4;
    const int qs = (q ^ ((r >> 1) & 3)) * 8;    // swizzled read granule offset (u16)
    const int a0 = mt * 4;

    const int m0 = t >> 2;                           // staging row 0..63
    const int c8 = (((t & 3) ^ ((t >> 3) & 3))) * 8; // pre-swizzled source granule

    const u16* aB = xs + (size_t)b*XP*RS + ((a0 + (m0 >> 5))*XP + (m0 & 31))*512 + c8;
    const u16* bB = wbT + m0*512 + c8;

    f32x4 acc[4][8];
    #pragma unroll
    for (int i = 0; i < 4; ++i)
        #pragma unroll
        for (int j = 0; j < 8; ++j) { f32x4 z = {0.f,0.f,0.f,0.f}; acc[i][j] = z; }

    const int S = ntaps << 4;

    auto stage = [&](int s, int buf) {
        int tap = s >> 4;
        int aof = (tap == 0) ? aof0 : (tap == 1) ? aof1 : (tap == 2) ? aof2 : aof3;
        int bof = (tap == 0) ? bof0 : (tap == 1) ? bof1 : (tap == 2) ? bof2 : bof3;
        int k0 = (s & 15) << 5;
        const u16* pa = aB + aof + k0;
        const u16* pb = bB + bof + k0;
        u16* la = &sm[buf * 12288 + t * 8];
        gload16(pa,            la);              // A rows 0..63
        gload16(pa + 2*RS,     la + 2048);       // A rows 64..127
        gload16(pb,            la + 4096);       // B rows 0..63
        gload16(pb + 64*512,   la + 4096 + 2048);
        gload16(pb + 128*512,  la + 4096 + 4096);
        gload16(pb + 192*512,  la + 4096 + 6144);
    };

    stage(0, 0);

    int cur = 0;
    for (int s = 0; s < S; ++s) {
        // issue next stage FIRST, then counted-wait for the current one
        if (s + 1 < S) {
            stage(s + 1, cur ^ 1);
            asm volatile("s_waitcnt vmcnt(6)" ::: "memory");
        } else {
            asm volatile("s_waitcnt vmcnt(0)" ::: "memory");
        }
        __builtin_amdgcn_s_barrier();          // stage(s) visible to all waves

        const u16* smc = &sm[cur * 12288];
        bf16x8 af[4], bfr[8];
        #pragma unroll
        for (int mi = 0; mi < 4; ++mi)
            af[mi] = *reinterpret_cast<const bf16x8*>(&smc[(wm0 + mi*16 + r)*32 + qs]);
        #pragma unroll
        for (int ni = 0; ni < 8; ++ni)
            bfr[ni] = *reinterpret_cast<const bf16x8*>(&smc[4096 + (wn0 + ni*16 + r)*32 + qs]);

        asm volatile("s_waitcnt lgkmcnt(0)" ::: "memory");
        __builtin_amdgcn_sched_barrier(0);
        __builtin_amdgcn_s_barrier();          // all waves done reading buf cur

        __builtin_amdgcn_s_setprio(1);
        #pragma unroll
        for (int mi = 0; mi < 4; ++mi)
            #pragma unroll
            for (int ni = 0; ni < 8; ++ni)
                acc[mi][ni] = __builtin_amdgcn_mfma_f32_16x16x32_bf16(
                    af[mi], bfr[ni], acc[mi][ni], 0, 0, 0);
        __builtin_amdgcn_s_setprio(0);

        cur ^= 1;
    }

    // epilogue: val = acc*demod[b,co] + bias[co], write bf16 into padded channel-last y
    float dmv[8], bsv[8];
    #pragma unroll
    for (int ni = 0; ni < 8; ++ni) {
        int co = wn0 + ni*16 + r;
        dmv[ni] = demod[b*256 + co];
        bsv[ni] = bias[co];
    }
    #pragma unroll
    for (int mi = 0; mi < 4; ++mi) {
        #pragma unroll
        for (int rg = 0; rg < 4; ++rg) {
            int m = wm0 + mi*16 + q*4 + rg;
            int ar = a0 + (m >> 5), bc = m & 31;
            int oy = 2*ar + py + 2, ox = 2*bc + px + 2;
            size_t rowbase = (((size_t)b*YP + oy)*YP + ox)*256;
            #pragma unroll
            for (int ni = 0; ni < 8; ++ni) {
                int co = wn0 + ni*16 + r;
                float v = acc[mi][ni][rg] * dmv[ni] + bsv[ni];
                ypad[rowbase + co] = f2bf(v);
            }
        }
    }
}

// ---------------- blur: separable 5x5 binomial + lrelu*sqrt2, 4 rows/block ----------
// block = (cg, oyq, b): 4 output rows. Threads load 8 input rows once into regs,
// compute 4 vertical sums, stage in LDS planes, then horizontal + store NCHW f32.
__global__ __launch_bounds__(256)
void blur_kernel(const u16* __restrict__ ypad, float* __restrict__ out) {
    const int cg  = blockIdx.x;   // 0..3 (64-channel chunk)
    const int oyq = blockIdx.y;   // 0..15 (4 oy rows each)
    const int b   = blockIdx.z;
    const int t = threadIdx.x;
    __shared__ float vlds[4][68][65];   // [oy][cx][ch]

    const int cp  = t & 31;       // channel pair
    const int cxi = t >> 5;       // 0..7
    const int oy0 = oyq * 4;
    const u16* base = ypad + ((size_t)b*YP + oy0)*YP*256 + cg*64 + cp*2;

    #pragma unroll
    for (int j = 0; j < 9; ++j) {
        int cx = j*8 + cxi;
        if (cx < 68) {
            bool cxok = (cx >= 2 && cx <= 65);
            float r0[8], r1[8];
            #pragma unroll
            for (int rr = 0; rr < 8; ++rr) {
                int iy = oy0 + rr;
                bool ok = cxok && (iy >= 2) && (iy <= 65);
                u32 u = ok ? *reinterpret_cast<const u32*>(base + ((size_t)rr*YP + cx)*256) : 0u;
                r0[rr] = __uint_as_float(u << 16);
                r1[rr] = __uint_as_float(u & 0xffff0000u);
            }
            #pragma unroll
            for (int o = 0; o < 4; ++o) {
                float a0 = 0.0625f*(r0[o]+r0[o+4]) + 0.25f*(r0[o+1]+r0[o+3]) + 0.375f*r0[o+2];
                float a1 = 0.0625f*(r1[o]+r1[o+4]) + 0.25f*(r1[o+1]+r1[o+3]) + 0.375f*r1[o+2];
                vlds[o][cx][cp*2]     = a0;
                vlds[o][cx][cp*2 + 1] = a1;
            }
        }
    }
    __syncthreads();

    const int oxl = t & 63;
    const int cq  = t >> 6;       // 0..3
    #pragma unroll
    for (int o = 0; o < 4; ++o) {
        float* ob = out + (((size_t)b*256 + cg*64)*64 + (oy0 + o))*64;
        #pragma unroll
        for (int i = 0; i < 16; ++i) {
            int c = cq*16 + i;
            float v = 0.0625f*(vlds[o][oxl][c] + vlds[o][oxl+4][c])
                    + 0.25f*(vlds[o][oxl+1][c] + vlds[o][oxl+3][c])
                    + 0.375f*vlds[o][oxl+2][c];
            v = (v >= 0.f ? v : 0.2f*v) * 1.4142135623730951f;
            ob[(size_t)c*4096 + oxl] = v;
        }
    }
}

extern "C" void kernel_launch(void* const* d_in, const int* in_sizes, int n_in,
                              void* d_out, int out_size, void* d_ws, size_t ws_size,
                              hipStream_t stream) {
    const float* x      = (const float*)d_in[0];
    const float* s      = (const float*)d_in[1];
    const float* weight = (const float*)d_in[2];
    const float* bias   = (const float*)d_in[3];
    const float* mod_w  = (const float*)d_in[4];
    const float* mod_b  = (const float*)d_in[5];
    float* out = (float*)d_out;

    char* ws = (char*)d_ws;
    size_t off = 0;
    u16*   xs    = (u16*)(ws + off); off += XS_BYTES;
    u16*   ypad  = (u16*)(ws + off); off += YP_BYTES;
    u16*   wbT   = (u16*)(ws + off); off += WBT_BYTES;
    float* wsq   = (float*)(ws + off); off += WSQ_BYTES;
    float* style = (float*)(ws + off); off += STY_BYTES;
    float* demod = (float*)(ws + off); off += DEM_BYTES;
    if (ws_size < off) return;  // workspace too small -> visible correctness failure

    fuseA_kernel<<<576, 256, 0, stream>>>(s, mod_w, mod_b, weight, style, wsq);
    fuseB_kernel<<<2368, 256, 0, stream>>>(style, wsq, weight, demod, wbT);
    norm_kernel<<<dim3(33, 16), 256, 0, stream>>>(x, style, xs);
    conv_mfma_kernel<<<dim3(8, 64), 256, 0, stream>>>(xs, wbT, demod, bias, ypad);
    blur_kernel<<<dim3(4, 16, 16), 256, 0, stream>>>(ypad, out);
}

// Round 8
// 133.643 us; speedup vs baseline: 1.5166x; 1.0050x over previous
//
#include <hip/hip_runtime.h>

// StyleGAN2 modulated transposed conv block, MI355X bf16-MFMA implementation.
// R8: conv = 3-buffer rotation (72KB), ONE barrier/step, counted vmcnt(6),
//     NO forced lgkm drain (compiler interleaves ds_read with MFMA), stage
//     issued right after barrier. Rest unchanged from R7.

typedef unsigned short u16;
typedef unsigned int u32;
typedef __bf16 bf16x8 __attribute__((ext_vector_type(8)));
typedef u16 u16x8 __attribute__((ext_vector_type(8)));
typedef float f32x4 __attribute__((ext_vector_type(4)));

#define CIN 512
#define COUT 256
#define XP 33   // padded xs spatial (32 + 1)
#define YP 68   // padded y spatial (64 + 2*2)
#define RS (XP*512)   // xs row stride in u16 = 16896

#define XS_BYTES  (16u*33*33*512*2)        // 17,842,176
#define YP_BYTES  (16u*68*68*256*2)        // 37,879,808
#define WBT_BYTES (9u*256*512*2)           //  2,359,296
#define WSQ_BYTES (512u*256*4)             //    524,288
#define STY_BYTES (16u*512*4)              //     32,768
#define DEM_BYTES (16u*256*4)              //     16,384

__device__ __forceinline__ u16 f2bf(float f) {
    u32 u = __float_as_uint(f);
    u32 r = (u + 0x7fffu + ((u >> 16) & 1u)) >> 16;
    return (u16)r;
}

__device__ __forceinline__ void gload16(const void* g, void* l) {
    __builtin_amdgcn_global_load_lds(
        (const __attribute__((address_space(1))) u32*)g,
        (__attribute__((address_space(3))) u32*)l, 16, 0, 0);
}

// ---------------- fuseA: style (64 blocks) + wsq (512 blocks) -----------------------
__global__ __launch_bounds__(256)
void fuseA_kernel(const float* __restrict__ s, const float* __restrict__ mod_w,
                  const float* __restrict__ mod_b, const float* __restrict__ weight,
                  float* __restrict__ style, float* __restrict__ wsq) {
    int bid = blockIdx.x, t = threadIdx.x;
    if (bid < 64) {
        int b = bid >> 2, q = bid & 3;
        __shared__ float ss[512];
        for (int i = t; i < 512; i += 256) ss[i] = s[b*512 + i];
        __syncthreads();
        int ci = q*128 + (t >> 1);
        int kh = (t & 1) * 256;
        const float* row = mod_w + (size_t)ci * 512 + kh;
        const float* sh = ss + kh;
        float acc = 0.f;
        for (int k = 0; k < 256; k += 4) {
            float4 m = *reinterpret_cast<const float4*>(row + k);
            acc += m.x*sh[k] + m.y*sh[k+1] + m.z*sh[k+2] + m.w*sh[k+3];
        }
        acc += __shfl_xor(acc, 1);
        if (!(t & 1)) style[b*512 + ci] = acc * 0.04419417382415922f + mod_b[ci];
    } else {
        int idx = (bid - 64) * 256 + t;   // 512*256
        const float* p = weight + (size_t)idx * 9;
        float a = 0.f;
        #pragma unroll
        for (int i = 0; i < 9; ++i) { float v = p[i]; a += v * v; }
        wsq[idx] = a;
    }
}

// ---------------- fuseB: demod (64 blocks) + wbt (2304 blocks) ----------------------
__global__ __launch_bounds__(256)
void fuseB_kernel(const float* __restrict__ style, const float* __restrict__ wsq,
                  const float* __restrict__ weight, float* __restrict__ demod,
                  u16* __restrict__ wbT) {
    int bid = blockIdx.x, t = threadIdx.x;
    if (bid < 64) {
        int b = bid >> 2, q = bid & 3;
        __shared__ float st2[512];
        for (int i = t; i < 512; i += 256) { float v = style[b*512 + i]; st2[i] = v * v; }
        __syncthreads();
        int co = q*64 + (t >> 2);
        int kq = (t & 3) * 128;
        float acc = 0.f;
        for (int ci = kq; ci < kq + 128; ++ci) acc += st2[ci] * wsq[ci*256 + co];
        acc += __shfl_xor(acc, 1);
        acc += __shfl_xor(acc, 2);
        if (!(t & 3)) demod[b*256 + co] = rsqrtf(acc * (1.0f/4608.0f) + 1e-8f);
    } else {
        int id = bid - 64;               // 0..2303
        int p = id >> 8, co = id & 255;
        u16* dst = wbT + ((size_t)p*256 + co)*512;
        const float* srcb = weight + co*9 + p;
        dst[t]       = f2bf(srcb[(size_t)t * 2304]);
        dst[t + 256] = f2bf(srcb[(size_t)(t + 256) * 2304]);
    }
}

// ---------------- norm: xs[b][h][w][ci] = x*rsqrt(mean_ci x^2 + eps)*style/sqrt4608 -
__global__ __launch_bounds__(256)
void norm_kernel(const float* __restrict__ x, const float* __restrict__ style,
                 u16* __restrict__ xs) {
    int h = blockIdx.x, b = blockIdx.y;
    int t = threadIdx.x;
    u16* xrow = xs + ((size_t)b*XP + h)*XP*512;
    if (h == 32) {                       // zero entire pad row (33*512 u16)
        u16x8 z = {0,0,0,0,0,0,0,0};
        for (int i = t; i < 2112; i += 256)
            reinterpret_cast<u16x8*>(xrow)[i] = z;
        return;
    }
    __shared__ float red[8][32];
    __shared__ float sscale[32];
    __shared__ float sstyle[512];
    __shared__ u16 tile[32*512];
    for (int i = t; i < 512; i += 256)
        sstyle[i] = style[b*512 + i] * 0.014731391274719739f;  // 1/sqrt(4608)
    int w = t & 31, cg = t >> 5;
    const float* xb = x + ((size_t)b*512*32 + h)*32;   // + ci*1024 + w

    float vv[64];
    float a = 0.f;
    #pragma unroll
    for (int i = 0; i < 64; ++i) {
        float v = xb[(size_t)(8*i + cg)*1024 + w];
        vv[i] = v;
        a += v * v;
    }
    red[cg][w] = a;
    __syncthreads();
    if (t < 32) {
        float s2 = 0.f;
        #pragma unroll
        for (int g = 0; g < 8; ++g) s2 += red[g][t];
        sscale[t] = rsqrtf(s2 * (1.0f/512.0f) + 1e-8f);
    }
    __syncthreads();
    float sc = sscale[w];
    #pragma unroll
    for (int i = 0; i < 64; ++i) {
        int ci = 8*i + cg;
        float v = vv[i] * sc * sstyle[ci];
        tile[w*512 + ((i ^ (w & 7)) * 8 + cg)] = f2bf(v);
    }
    if (t < 64) {
        u16x8 z = {0,0,0,0,0,0,0,0};
        reinterpret_cast<u16x8*>(xrow + 32*512)[t] = z;
    }
    __syncthreads();
    int wv = t >> 6, gi = t & 63;
    #pragma unroll
    for (int rr = 0; rr < 32; rr += 4) {
        int w2 = rr + wv;
        u16x8 v = *reinterpret_cast<const u16x8*>(&tile[w2*512 + ((gi ^ (w2 & 7)) * 8)]);
        *reinterpret_cast<u16x8*>(&xrow[w2*512 + gi*8]) = v;
    }
}

// ---------------- conv: parity-class implicit GEMM, 128x256 tile, 3-buf 1-barrier ---
// class (py,px): y[2a+py, 2b+px] = sum_taps sum_ci xs[a+dy, b+dx, ci] * W[kh,kw][ci,co]
// 4 waves (2Mx2N), each 64Mx128N: 12 ds_read_b128 / 32 MFMA per K-step.
// Per step: vmcnt(6) -> barrier -> stage(s+2, buf s-1) -> reads+MFMA (compiler lgkm).
__global__ __launch_bounds__(256)
void conv_mfma_kernel(const u16* __restrict__ xs, const u16* __restrict__ wbT,
                      const float* __restrict__ demod, const float* __restrict__ bias,
                      u16* __restrict__ ypad) {
    // per buf (12288 u16 = 24KB): A[128][32] @0, B[256][32] @4096
    __shared__ __align__(16) u16 sm[3*12288];

    const int mt = blockIdx.x;         // 0..7  M-tile
    const int zz = blockIdx.y;         // 0..63
    // balanced mapping: ids 0..255 alt {cls3,cls2}; 256..511 alt {cls0,cls1}
    int cls, b;
    if (zz < 32) { cls = (zz & 1) ? 2 : 3; b = zz >> 1; }
    else         { cls = (zz & 1) ? 1 : 0; b = (zz - 32) >> 1; }
    const int py = cls >> 1, px = cls & 1;

    int ntaps;
    int aof0=0, aof1=0, aof2=0, aof3=0;
    int bof0=0, bof1=0, bof2=0, bof3=0;
    if (cls == 0)      { ntaps=1; aof0=0;        bof0=4*131072; }
    else if (cls == 1) { ntaps=2; aof0=512;      bof0=3*131072;
                                  aof1=0;        bof1=5*131072; }
    else if (cls == 2) { ntaps=2; aof0=RS;       bof0=1*131072;
                                  aof1=0;        bof1=7*131072; }
    else               { ntaps=4; aof0=RS+512;   bof0=0;
                                  aof1=RS;       bof1=2*131072;
                                  aof2=512;      bof2=6*131072;
                                  aof3=0;        bof3=8*131072; }

    const int t = threadIdx.x;
    const int lane = t & 63, wid = t >> 6;
    const int wm0 = (wid >> 1) * 64;       // M half: 0 / 64
    const int wn0 = (wid & 1) * 128;       // N half: 0 / 128
    const int r = lane & 15, q = lane >> 4;
    const int qs = (q ^ ((r >> 1) & 3)) * 8;    // swizzled read granule offset (u16)
    const int a0 = mt * 4;

    const int m0 = t >> 2;                           // staging row 0..63
    const int c8 = (((t & 3) ^ ((t >> 3) & 3))) * 8; // pre-swizzled source granule

    const u16* aB = xs + (size_t)b*XP*RS + ((a0 + (m0 >> 5))*XP + (m0 & 31))*512 + c8;
    const u16* bB = wbT + m0*512 + c8;

    f32x4 acc[4][8];
    #pragma unroll
    for (int i = 0; i < 4; ++i)
        #pragma unroll
        for (int j = 0; j < 8; ++j) { f32x4 z = {0.f,0.f,0.f,0.f}; acc[i][j] = z; }

    const int S = ntaps << 4;

    auto stage = [&](int s, int buf) {
        int tap = s >> 4;
        int aof = (tap == 0) ? aof0 : (tap == 1) ? aof1 : (tap == 2) ? aof2 : aof3;
        int bof = (tap == 0) ? bof0 : (tap == 1) ? bof1 : (tap == 2) ? bof2 : bof3;
        int k0 = (s & 15) << 5;
        const u16* pa = aB + aof + k0;
        const u16* pb = bB + bof + k0;
        u16* la = &sm[buf * 12288 + t * 8];
        gload16(pa,            la);              // A rows 0..63
        gload16(pa + 2*RS,     la + 2048);       // A rows 64..127
        gload16(pb,            la + 4096);       // B rows 0..63
        gload16(pb + 64*512,   la + 4096 + 2048);
        gload16(pb + 128*512,  la + 4096 + 4096);
        gload16(pb + 192*512,  la + 4096 + 6144);
    };

    stage(0, 0);
    stage(1, 1);

    int cur = 0;
    for (int s = 0; s < S; ++s) {
        // wait for stage(s); stage(s+1) stays in flight
        if (s + 1 < S) asm volatile("s_waitcnt vmcnt(6)" ::: "memory");
        else           asm volatile("s_waitcnt vmcnt(0)" ::: "memory");
        __builtin_amdgcn_s_barrier();
        // all waves past barrier => their step s-1 reads of buf (cur+2)%3 retired
        if (s + 2 < S) {
            int b2 = cur + 2; if (b2 >= 3) b2 -= 3;
            stage(s + 2, b2);
        }

        const u16* smc = &sm[cur * 12288];
        bf16x8 af[4], bfr[8];
        #pragma unroll
        for (int mi = 0; mi < 4; ++mi)
            af[mi] = *reinterpret_cast<const bf16x8*>(&smc[(wm0 + mi*16 + r)*32 + qs]);
        #pragma unroll
        for (int ni = 0; ni < 8; ++ni)
            bfr[ni] = *reinterpret_cast<const bf16x8*>(&smc[4096 + (wn0 + ni*16 + r)*32 + qs]);

        // no forced lgkm drain: compiler interleaves reads with MFMAs
        __builtin_amdgcn_s_setprio(1);
        #pragma unroll
        for (int mi = 0; mi < 4; ++mi)
            #pragma unroll
            for (int ni = 0; ni < 8; ++ni)
                acc[mi][ni] = __builtin_amdgcn_mfma_f32_16x16x32_bf16(
                    af[mi], bfr[ni], acc[mi][ni], 0, 0, 0);
        __builtin_amdgcn_s_setprio(0);

        cur = (cur == 2) ? 0 : cur + 1;
    }

    // epilogue: val = acc*demod[b,co] + bias[co], write bf16 into padded channel-last y
    float dmv[8], bsv[8];
    #pragma unroll
    for (int ni = 0; ni < 8; ++ni) {
        int co = wn0 + ni*16 + r;
        dmv[ni] = demod[b*256 + co];
        bsv[ni] = bias[co];
    }
    #pragma unroll
    for (int mi = 0; mi < 4; ++mi) {
        #pragma unroll
        for (int rg = 0; rg < 4; ++rg) {
            int m = wm0 + mi*16 + q*4 + rg;
            int ar = a0 + (m >> 5), bc = m & 31;
            int oy = 2*ar + py + 2, ox = 2*bc + px + 2;
            size_t rowbase = (((size_t)b*YP + oy)*YP + ox)*256;
            #pragma unroll
            for (int ni = 0; ni < 8; ++ni) {
                int co = wn0 + ni*16 + r;
                float v = acc[mi][ni][rg] * dmv[ni] + bsv[ni];
                ypad[rowbase + co] = f2bf(v);
            }
        }
    }
}

// ---------------- blur: separable 5x5 binomial + lrelu*sqrt2, 4 rows/block ----------
__global__ __launch_bounds__(256)
void blur_kernel(const u16* __restrict__ ypad, float* __restrict__ out) {
    const int cg  = blockIdx.x;   // 0..3 (64-channel chunk)
    const int oyq = blockIdx.y;   // 0..15 (4 oy rows each)
    const int b   = blockIdx.z;
    const int t = threadIdx.x;
    __shared__ float vlds[4][68][65];   // [oy][cx][ch]

    const int cp  = t & 31;       // channel pair
    const int cxi = t >> 5;       // 0..7
    const int oy0 = oyq * 4;
    const u16* base = ypad + ((size_t)b*YP + oy0)*YP*256 + cg*64 + cp*2;

    #pragma unroll
    for (int j = 0; j < 9; ++j) {
        int cx = j*8 + cxi;
        if (cx < 68) {
            bool cxok = (cx >= 2 && cx <= 65);
            float r0[8], r1[8];
            #pragma unroll
            for (int rr = 0; rr < 8; ++rr) {
                int iy = oy0 + rr;
                bool ok = cxok && (iy >= 2) && (iy <= 65);
                u32 u = ok ? *reinterpret_cast<const u32*>(base + ((size_t)rr*YP + cx)*256) : 0u;
                r0[rr] = __uint_as_float(u << 16);
                r1[rr] = __uint_as_float(u & 0xffff0000u);
            }
            #pragma unroll
            for (int o = 0; o < 4; ++o) {
                float a0 = 0.0625f*(r0[o]+r0[o+4]) + 0.25f*(r0[o+1]+r0[o+3]) + 0.375f*r0[o+2];
                float a1 = 0.0625f*(r1[o]+r1[o+4]) + 0.25f*(r1[o+1]+r1[o+3]) + 0.375f*r1[o+2];
                vlds[o][cx][cp*2]     = a0;
                vlds[o][cx][cp*2 + 1] = a1;
            }
        }
    }
    __syncthreads();

    const int oxl = t & 63;
    const int cq  = t >> 6;       // 0..3
    #pragma unroll
    for (int o = 0; o < 4; ++o) {
        float* ob = out + (((size_t)b*256 + cg*64)*64 + (oy0 + o))*64;
        #pragma unroll
        for (int i = 0; i < 16; ++i) {
            int c = cq*16 + i;
            float v = 0.0625f*(vlds[o][oxl][c] + vlds[o][oxl+4][c])
                    + 0.25f*(vlds[o][oxl+1][c] + vlds[o][oxl+3][c])
                    + 0.375f*vlds[o][oxl+2][c];
            v = (v >= 0.f ? v : 0.2f*v) * 1.4142135623730951f;
            ob[(size_t)c*4096 + oxl] = v;
        }
    }
}

extern "C" void kernel_launch(void* const* d_in, const int* in_sizes, int n_in,
                              void* d_out, int out_size, void* d_ws, size_t ws_size,
                              hipStream_t stream) {
    const float* x      = (const float*)d_in[0];
    const float* s      = (const float*)d_in[1];
    const float* weight = (const float*)d_in[2];
    const float* bias   = (const float*)d_in[3];
    const float* mod_w  = (const float*)d_in[4];
    const float* mod_b  = (const float*)d_in[5];
    float* out = (float*)d_out;

    char* ws = (char*)d_ws;
    size_t off = 0;
    u16*   xs    = (u16*)(ws + off); off += XS_BYTES;
    u16*   ypad  = (u16*)(ws + off); off += YP_BYTES;
    u16*   wbT   = (u16*)(ws + off); off += WBT_BYTES;
    float* wsq   = (float*)(ws + off); off += WSQ_BYTES;
    float* style = (float*)(ws + off); off += STY_BYTES;
    float* demod = (float*)(ws + off); off += DEM_BYTES;
    if (ws_size < off) return;  // workspace too small -> visible correctness failure

    fuseA_kernel<<<576, 256, 0, stream>>>(s, mod_w, mod_b, weight, style, wsq);
    fuseB_kernel<<<2368, 256, 0, stream>>>(style, wsq, weight, demod, wbT);
    norm_kernel<<<dim3(33, 16), 256, 0, stream>>>(x, style, xs);
    conv_mfma_kernel<<<dim3(8, 64), 256, 0, stream>>>(xs, wbT, demod, bias, ypad);
    blur_kernel<<<dim3(4, 16, 16), 256, 0, stream>>>(ypad, out);
}